// Round 9
// baseline (139.604 us; speedup 1.0000x reference)
//
#include <hip/hip_runtime.h>

typedef unsigned short u16;
typedef unsigned int u32;
typedef __bf16 bf16x8 __attribute__((ext_vector_type(8)));
typedef float f32x16 __attribute__((ext_vector_type(16)));

#define C2 (-7.213475204444817f) /* -5/ln2 : exp(-5 t^2) = exp2(C2 t^2) */
#define T1C 0.28650480f          /* e^-1.25 */
#define T2C 0.0067379470f        /* e^-5    */

__device__ __forceinline__ u16 f2bf(float f) {
  u32 u = __float_as_uint(f);
  return (u16)((u + 0x7FFFu + ((u >> 16) & 1u)) >> 16);  // RNE
}

__device__ __forceinline__ f32x16 mfma16(uint4 a, uint4 b, f32x16 c) {
  return __builtin_amdgcn_mfma_f32_32x32x16_bf16(
      __builtin_bit_cast(bf16x8, a), __builtin_bit_cast(bf16x8, b), c, 0, 0, 0);
}

// ---------------------------------------------------------------------------
// Prep (unchanged from R7/R8; validated): f32 weights -> bf16, per-16k-chunk
// fragment order. wst3 granule(c, g) 16 B, g = s*256 + nq*64 + l:
//   content = W_s[k = c*16 + (l>>5)*8 + 0..8)[u = nq*32 + (l&31)]
// ---------------------------------------------------------------------------
__global__ __launch_bounds__(256) void kan_prep(const float* __restrict__ wb,
                                                const float* __restrict__ ws,
                                                u16* __restrict__ wst3) {
  __shared__ u16 tile[6][16][130];
  const int t = threadIdx.x;
  const int c = blockIdx.x;
#pragma unroll
  for (int it = 0; it < 8; ++it) {
    int idx = it * 256 + t;
    int d = idx >> 7, u = idx & 127;
    size_t base = (size_t)(c * 16 + d) * 128 + u;
    const float* p = ws + base * 8;
    float4 v0 = *(const float4*)p;
    float g4 = p[4];
    tile[0][d][u] = f2bf(v0.x);
    tile[1][d][u] = f2bf(v0.y);
    tile[2][d][u] = f2bf(v0.z);
    tile[3][d][u] = f2bf(v0.w);
    tile[4][d][u] = f2bf(g4);
    tile[5][d][u] = f2bf(wb[base]);
  }
  __syncthreads();
#pragma unroll
  for (int i = 0; i < 6; ++i) {
    int g = i * 256 + t;
    int s = g >> 8, r = g & 255;
    int nq = r >> 6, l = r & 63;
    int u = nq * 32 + (l & 31);
    int dbase = (l >> 5) * 8;
    u32 q[4];
#pragma unroll
    for (int j = 0; j < 4; ++j) {
      u32 lo = tile[s][dbase + 2 * j][u];
      u32 hi = tile[s][dbase + 2 * j + 1][u];
      q[j] = lo | (hi << 16);
    }
    uint4 w4; w4.x = q[0]; w4.y = q[1]; w4.z = q[2]; w4.w = q[3];
    *(uint4*)(wst3 + (size_t)c * 12288 + (size_t)g * 8) = w4;
  }
}

// ---------------------------------------------------------------------------
// Main R9: grid 256, block 1024 = 16 waves (wn 0..3, kq 0..3) -> 4 waves/SIMD
// from a single resident block.  Wave tile 64m x 32n; 4-way k-split (wave kq
// owns k-slice kq*16 of each BK=64 chunk; partials merged in LDS epilogue).
// B: DIRECT from global (wst3 fragment-ordered, per-wave vmcnt pipelining,
// no barrier-coupled staging) — (wn,kq) partitions B: zero duplication.
// A (rbf subs 0..4 + bf16(x) sub 5) in LDS only: dbuf 2 x 48 KB.
//   A byte = s*8192 + gm*4096 + kq*1024 + kh*512 + slot*16 (+half*8 writer),
//   slot = (m&31) ^ (kq*2+kh).  Writer: thread t -> row r=(t>>6)*4+(t&3),
//   k-quad q4=(t>>2)&15 (x loads 256B-contiguous per row; LDS writes <=2-way
//   per phase).  mfma A[m=lane&31][k=(lane>>5)*8+j]; C/D col=lane&31,
//   row=(reg&3)+8*(reg>>2)+4*(lane>>5)   (all validated R2-R8).
// acc: 0/1 spline gm0/gm1, 2/3 base gm0/gm1.
// ---------------------------------------------------------------------------
__global__ __launch_bounds__(1024, 4) void kan_main(const float* __restrict__ x,
                                                    const u16* __restrict__ wst3,
                                                    float* __restrict__ out) {
  __shared__ __align__(16) char lds[98304];  // 2 x 49152

  const int t = threadIdx.x;
  const int lane = t & 63;
  const int w = t >> 6;   // 0..15
  const int wn = w & 3;   // n-quarter
  const int kq = w >> 2;  // k-slice within BK=64
  const int b0 = blockIdx.x * 64;

  f32x16 acc[4];
#pragma unroll
  for (int i = 0; i < 4; ++i)
#pragma unroll
    for (int j = 0; j < 16; ++j) acc[i][j] = 0.f;

  // ---- rbf writer: thread t -> row r, k-quad q4 (4 consecutive k)
  const int r = w * 4 + (t & 3);
  const int q4 = (t >> 2) & 15;
  const float* xp = x + (size_t)(b0 + r) * 1024 + q4 * 4;
  const int kqw = q4 >> 2, khw = (q4 >> 1) & 1, half = q4 & 1;
  const u32 aw = (u32)((r >> 5) * 4096 + kqw * 1024 + khw * 512 +
                       (((r & 31) ^ (kqw * 2 + khw)) << 4) + half * 8);  // + s*8192

  // ---- B source (byte): + i*98304 + s*4096
  const char* bsrc = (const char*)wst3 + kq * 24576 + wn * 1024 + lane * 16;

  // ---- A reader (byte): + s*8192 + gm*4096
  const int kh = lane >> 5;
  const u32 ar = (u32)(kq * 1024 + kh * 512 +
                       (((lane & 31) ^ (kq * 2 + kh)) << 4));

  auto rbf_write = [&](char* buf, float4 xa) {
    float xf[4] = {xa.x, xa.y, xa.z, xa.w};
    u32 pk[6][2];
#pragma unroll
    for (int pp = 0; pp < 2; ++pp) {
      u32 lo6[6], hi6[6];
#pragma unroll
      for (int e = 0; e < 2; ++e) {
        float xv = xf[2 * pp + e];
        float t0 = C2 * xv;
        float P = __builtin_amdgcn_exp2f(t0 * xv);  // e^{-5x^2}
        float Qp = __builtin_amdgcn_exp2f(-t0);     // e^{+5x}
        float Qm = __builtin_amdgcn_exp2f(t0);      // e^{-5x}
        float PQ = P * Qp, PQm = P * Qm;
        u32* dst = e ? hi6 : lo6;
        dst[0] = __float_as_uint(PQm * Qm * T2C) + 0x8000u;
        dst[1] = __float_as_uint(PQm * T1C) + 0x8000u;
        dst[2] = __float_as_uint(P) + 0x8000u;
        dst[3] = __float_as_uint(PQ * T1C) + 0x8000u;
        dst[4] = __float_as_uint(PQ * Qp * T2C) + 0x8000u;
        dst[5] = __float_as_uint(xv) + 0x8000u;
      }
#pragma unroll
      for (int s = 0; s < 6; ++s)
        pk[s][pp] = __builtin_amdgcn_perm(hi6[s], lo6[s], 0x07060302);
    }
#pragma unroll
    for (int s = 0; s < 6; ++s) {
      uint2 v; v.x = pk[s][0]; v.y = pk[s][1];
      *(uint2*)(buf + s * 8192 + aw) = v;
    }
  };

  // ---- prologue
  float4 xc = *(const float4*)(xp);
  rbf_write(lds, xc);
  xc = *(const float4*)(xp + 64);
  __syncthreads();

  for (int i = 0; i < 16; ++i) {
    char* cur = lds + (size_t)(i & 1) * 49152;
    char* nxt = lds + (size_t)((i + 1) & 1) * 49152;
    const char* bc = bsrc + (size_t)i * 98304;

    uint4 av[6], bv[3];
    // ---- half 0: subs 0..2 (spline)
#pragma unroll
    for (int s = 0; s < 3; ++s) {
      bv[s] = *(const uint4*)(bc + s * 4096);
      av[2 * s] = *(const uint4*)(cur + s * 8192 + ar);
      av[2 * s + 1] = *(const uint4*)(cur + s * 8192 + 4096 + ar);
    }
    if (i < 15) {
      rbf_write(nxt, xc);
      if (i < 14) xc = *(const float4*)(xp + (i + 2) * 64);
    }
#pragma unroll
    for (int s = 0; s < 3; ++s) {
      acc[0] = mfma16(av[2 * s], bv[s], acc[0]);
      acc[1] = mfma16(av[2 * s + 1], bv[s], acc[1]);
    }
    // ---- half 1: subs 3..5 (3,4 spline; 5 base)
#pragma unroll
    for (int s = 3; s < 6; ++s) {
      int j = 2 * (s - 3);
      bv[s - 3] = *(const uint4*)(bc + s * 4096);
      av[j] = *(const uint4*)(cur + s * 8192 + ar);
      av[j + 1] = *(const uint4*)(cur + s * 8192 + 4096 + ar);
    }
#pragma unroll
    for (int s = 3; s < 5; ++s) {
      int j = 2 * (s - 3);
      acc[0] = mfma16(av[j], bv[s - 3], acc[0]);
      acc[1] = mfma16(av[j + 1], bv[s - 3], acc[1]);
    }
    acc[2] = mfma16(av[4], bv[2], acc[2]);
    acc[3] = mfma16(av[5], bv[2], acc[3]);
    __syncthreads();
  }

  // ---- epilogue: merge kq partials (4-way) per wn; 2 rounds over gm.
#pragma unroll
  for (int g = 0; g < 2; ++g) {
    if (kq != 0) {
      char* slab = lds + ((kq - 1) * 4 + wn) * 8192;
#pragma unroll
      for (int rq = 0; rq < 4; ++rq) {
        *(float4*)(slab + rq * 1024 + lane * 16) =
            make_float4(acc[g][4 * rq], acc[g][4 * rq + 1],
                        acc[g][4 * rq + 2], acc[g][4 * rq + 3]);
        *(float4*)(slab + 4096 + rq * 1024 + lane * 16) =
            make_float4(acc[2 + g][4 * rq], acc[2 + g][4 * rq + 1],
                        acc[2 + g][4 * rq + 2], acc[2 + g][4 * rq + 3]);
      }
    }
    __syncthreads();
    if (kq == 0) {
#pragma unroll
      for (int p = 1; p < 4; ++p) {
        const char* slab = lds + ((p - 1) * 4 + wn) * 8192;
#pragma unroll
        for (int rq = 0; rq < 4; ++rq) {
          float4 vs = *(const float4*)(slab + rq * 1024 + lane * 16);
          float4 vb = *(const float4*)(slab + 4096 + rq * 1024 + lane * 16);
          acc[g][4 * rq] += vs.x; acc[g][4 * rq + 1] += vs.y;
          acc[g][4 * rq + 2] += vs.z; acc[g][4 * rq + 3] += vs.w;
          acc[2 + g][4 * rq] += vb.x; acc[2 + g][4 * rq + 1] += vb.y;
          acc[2 + g][4 * rq + 2] += vb.z; acc[2 + g][4 * rq + 3] += vb.w;
        }
      }
      const int col = wn * 32 + (lane & 31);
#pragma unroll
      for (int reg = 0; reg < 16; ++reg) {
        int row = g * 32 + (reg & 3) + 8 * (reg >> 2) + 4 * (lane >> 5);
        float z = acc[2 + g][reg];
        float sv = z / (1.0f + __expf(-z));
        out[(size_t)(b0 + row) * 128 + col] = sv + acc[g][reg];
      }
    }
    __syncthreads();
  }
}

extern "C" void kernel_launch(void* const* d_in, const int* in_sizes, int n_in,
                              void* d_out, int out_size, void* d_ws, size_t ws_size,
                              hipStream_t stream) {
  const float* x  = (const float*)d_in[0];   // [16384][1024] f32
  const float* wb = (const float*)d_in[1];   // [1024][128]   f32
  const float* ws = (const float*)d_in[2];   // [1024][128][8] f32
  u16* wst3 = (u16*)d_ws;                    // [64][1536] granules, 1.5 MB
  float* out = (float*)d_out;                // [16384][128]  f32

  kan_prep<<<dim3(64), 256, 0, stream>>>(wb, ws, wst3);
  kan_main<<<dim3(256), 1024, 0, stream>>>(x, wst3, out);
}